// Round 1
// baseline (986.268 us; speedup 1.0000x reference)
//
#include <hip/hip_runtime.h>
#include <hip/hip_bf16.h>

#define N_NODES 50000
#define N_EDGES 800000
#define TOT_E   (N_EDGES + N_NODES)   // edges + self loops = 850000
#define NEG_SLOPE 0.2f

// ---------------------------------------------------------------- CSR build
__global__ void k_hist(const int* __restrict__ dstp, int* __restrict__ rowptr) {
    int e = blockIdx.x * blockDim.x + threadIdx.x;
    if (e < TOT_E) {
        int d = (e < N_EDGES) ? dstp[e] : (e - N_EDGES);
        atomicAdd(&rowptr[d + 1], 1);
    }
}

// single-block inclusive scan over rowptr[1..N]; also fills cursor[] = start offsets
__global__ void k_scan(int* __restrict__ rowptr, int* __restrict__ cursor) {
    __shared__ int sh[1024];
    __shared__ int carry_sh;
    int tid = threadIdx.x;
    if (tid == 0) { carry_sh = 0; cursor[0] = 0; }
    __syncthreads();
    for (int base = 0; base < N_NODES; base += 1024) {
        int i = base + tid;
        int v = (i < N_NODES) ? rowptr[i + 1] : 0;
        sh[tid] = v;
        __syncthreads();
        for (int off = 1; off < 1024; off <<= 1) {
            int t = (tid >= off) ? sh[tid - off] : 0;
            __syncthreads();
            sh[tid] += t;
            __syncthreads();
        }
        int carry = carry_sh;
        if (i < N_NODES) {
            int val = carry + sh[tid];
            rowptr[i + 1] = val;
            cursor[i + 1] = val;   // cursor has N+1 slots; [n] = start of node n
        }
        __syncthreads();
        if (tid == 1023) carry_sh = carry + sh[1023];
        __syncthreads();
    }
}

__global__ void k_scatter(const int* __restrict__ dstp, int* __restrict__ cursor,
                          int* __restrict__ eidx) {
    int e = blockIdx.x * blockDim.x + threadIdx.x;
    if (e < TOT_E) {
        int d = (e < N_EDGES) ? dstp[e] : (e - N_EDGES);
        int pos = atomicAdd(&cursor[d], 1);
        eidx[pos] = e;
    }
}

// ------------------------------------------------- fused dual linear (X@Wa, X@Wb)
// K = 128, OUT = 128 for both matrices. 8 nodes per block, 256 threads:
// threads 0..127 compute Wa columns, 128..255 compute Wb columns.
__global__ __launch_bounds__(256) void k_linear(const float* __restrict__ X,
                                                const float* __restrict__ Wa,
                                                const float* __restrict__ Wb,
                                                float* __restrict__ outA,
                                                float* __restrict__ outB) {
    __shared__ float xs[8][128];
    int n0 = blockIdx.x * 8;
    int tid = threadIdx.x;
    for (int r = tid; r < 8 * 128; r += 256)
        ((float*)xs)[r] = X[(size_t)n0 * 128 + r];
    __syncthreads();

    int j = tid & 127;
    const float* W = (tid < 128) ? Wa : Wb;
    float* out = (tid < 128) ? outA : outB;
    float acc[8] = {0.f, 0.f, 0.f, 0.f, 0.f, 0.f, 0.f, 0.f};
    for (int k = 0; k < 128; k += 4) {
        float w0 = W[(k + 0) * 128 + j];
        float w1 = W[(k + 1) * 128 + j];
        float w2 = W[(k + 2) * 128 + j];
        float w3 = W[(k + 3) * 128 + j];
#pragma unroll
        for (int nd = 0; nd < 8; ++nd) {
            float4 xv = *(const float4*)&xs[nd][k];
            acc[nd] += xv.x * w0 + xv.y * w1 + xv.z * w2 + xv.w * w3;
        }
    }
#pragma unroll
    for (int nd = 0; nd < 8; ++nd)
        out[(size_t)(n0 + nd) * 128 + j] = acc[nd];
}

// ------------------------------------------------- per-edge attention logits
// one wave (64 lanes) per edge; ar[e*H + h] = att[h]·leakyrelu(xl[src]+xr[dst])
template <int H, int C>
__global__ __launch_bounds__(256) void k_edge(const int* __restrict__ srcp,
                                              const int* __restrict__ dstp,
                                              const float* __restrict__ xl,
                                              const float* __restrict__ xr,
                                              const float* __restrict__ att,
                                              float* __restrict__ ar) {
    int w = (blockIdx.x * 256 + threadIdx.x) >> 6;
    int lane = threadIdx.x & 63;
    if (w >= TOT_E) return;
    int s = (w < N_EDGES) ? srcp[w] : (w - N_EDGES);
    int d = (w < N_EDGES) ? dstp[w] : (w - N_EDGES);
    const float* xls = xl + (size_t)s * 128;
    const float* xrd = xr + (size_t)d * 128;
#pragma unroll
    for (int h = 0; h < H; ++h) {
        float sum = 0.f;
#pragma unroll
        for (int cc = 0; cc < C; cc += 64) {
            int c = cc + lane;
            float v = xls[h * C + c] + xrd[h * C + c];
            v = (v > 0.f) ? v : NEG_SLOPE * v;
            sum += v * att[h * C + c];
        }
#pragma unroll
        for (int off = 32; off > 0; off >>= 1)
            sum += __shfl_xor(sum, off, 64);
        if (lane == 0) ar[(size_t)w * H + h] = sum;
    }
}

// ------------------------------------------------- per-node softmax + aggregate
// one wave per node: exact segment max, exp-sum, weighted sum of xl[src],
// normalize, +bias, ELU. Element mapping: lane -> elem lane (head 0),
// lane+64 -> elem lane+64 (head H-1). No atomics, one coalesced store.
template <int H>
__global__ __launch_bounds__(256) void k_node(const int* __restrict__ rowptr,
                                              const int* __restrict__ eidx,
                                              const int* __restrict__ srcp,
                                              const float* __restrict__ ar,
                                              const float* __restrict__ xl,
                                              const float* __restrict__ bias,
                                              float* __restrict__ out) {
    int n = (blockIdx.x * 256 + threadIdx.x) >> 6;
    int lane = threadIdx.x & 63;
    if (n >= N_NODES) return;
    int start = rowptr[n], end = rowptr[n + 1];

    float m[H];
#pragma unroll
    for (int h = 0; h < H; ++h) m[h] = -1e30f;
    for (int i = start + lane; i < end; i += 64) {
        int eid = eidx[i];
#pragma unroll
        for (int h = 0; h < H; ++h) m[h] = fmaxf(m[h], ar[(size_t)eid * H + h]);
    }
#pragma unroll
    for (int h = 0; h < H; ++h)
#pragma unroll
        for (int off = 32; off > 0; off >>= 1)
            m[h] = fmaxf(m[h], __shfl_xor(m[h], off, 64));

    float den[H];
#pragma unroll
    for (int h = 0; h < H; ++h) den[h] = 0.f;
    float acc0 = 0.f, acc1 = 0.f;
    for (int i = start; i < end; ++i) {
        int eid = eidx[i];
        int s = (eid < N_EDGES) ? srcp[eid] : (eid - N_EDGES);
        float p[H];
#pragma unroll
        for (int h = 0; h < H; ++h) {
            p[h] = __expf(ar[(size_t)eid * H + h] - m[h]);
            den[h] += p[h];
        }
        const float* xs = xl + (size_t)s * 128;
        acc0 += p[0] * xs[lane];
        acc1 += p[H - 1] * xs[64 + lane];
    }
    float o0 = acc0 / (den[0] + 1e-16f) + bias[lane];
    float o1 = acc1 / (den[H - 1] + 1e-16f) + bias[64 + lane];
    o0 = (o0 > 0.f) ? o0 : (__expf(o0) - 1.f);   // ELU
    o1 = (o1 > 0.f) ? o1 : (__expf(o1) - 1.f);
    out[(size_t)n * 128 + lane] = o0;
    out[(size_t)n * 128 + 64 + lane] = o1;
}

// ---------------------------------------------------------------- launch
extern "C" void kernel_launch(void* const* d_in, const int* in_sizes, int n_in,
                              void* d_out, int out_size, void* d_ws, size_t ws_size,
                              hipStream_t stream) {
    const float* x    = (const float*)d_in[0];
    const int*   ei   = (const int*)d_in[1];
    const float* Wl1  = (const float*)d_in[2];
    const float* Wr1  = (const float*)d_in[3];
    const float* att1 = (const float*)d_in[4];
    const float* b1   = (const float*)d_in[5];
    const float* Wl2  = (const float*)d_in[6];
    const float* Wr2  = (const float*)d_in[7];
    const float* att2 = (const float*)d_in[8];
    const float* b2   = (const float*)d_in[9];
    const int* srcp = ei;
    const int* dstp = ei + N_EDGES;

    char* ws = (char*)d_ws;
    size_t off = 0;
    auto alloc = [&](size_t bytes) {
        void* p = ws + off;
        off = (off + bytes + 255) & ~(size_t)255;
        return p;
    };
    int*   rowptr = (int*)alloc((N_NODES + 1) * sizeof(int));
    int*   cursor = (int*)alloc((N_NODES + 1) * sizeof(int));
    int*   eidx   = (int*)alloc((size_t)TOT_E * sizeof(int));
    float* ar     = (float*)alloc((size_t)TOT_E * 2 * sizeof(float));
    float* xl     = (float*)alloc((size_t)N_NODES * 128 * sizeof(float));
    float* xr     = (float*)alloc((size_t)N_NODES * 128 * sizeof(float));
    float* h1     = (float*)alloc((size_t)N_NODES * 128 * sizeof(float));

    // CSR build (graph is identical for both layers)
    hipMemsetAsync(rowptr, 0, (N_NODES + 1) * sizeof(int), stream);
    k_hist<<<(TOT_E + 255) / 256, 256, 0, stream>>>(dstp, rowptr);
    k_scan<<<1, 1024, 0, stream>>>(rowptr, cursor);
    k_scatter<<<(TOT_E + 255) / 256, 256, 0, stream>>>(dstp, cursor, eidx);

    // layer 1: heads=2, C=64, concat
    k_linear<<<N_NODES / 8, 256, 0, stream>>>(x, Wl1, Wr1, xl, xr);
    k_edge<2, 64><<<(TOT_E + 3) / 4, 256, 0, stream>>>(srcp, dstp, xl, xr, att1, ar);
    k_node<2><<<(N_NODES + 3) / 4, 256, 0, stream>>>(rowptr, eidx, srcp, ar, xl, b1, h1);

    // layer 2: heads=1, C=128, mean(1 head) = identity
    k_linear<<<N_NODES / 8, 256, 0, stream>>>(h1, Wl2, Wr2, xl, xr);
    k_edge<1, 128><<<(TOT_E + 3) / 4, 256, 0, stream>>>(srcp, dstp, xl, xr, att2, ar);
    k_node<1><<<(N_NODES + 3) / 4, 256, 0, stream>>>(rowptr, eidx, srcp, ar, xl, b2, (float*)d_out);
}

// Round 2
// 608.268 us; speedup vs baseline: 1.6214x; 1.6214x over previous
//
#include <hip/hip_runtime.h>
#include <hip/hip_bf16.h>

#define N_NODES 50000
#define N_EDGES 800000
#define TOT_E   (N_EDGES + N_NODES)   // edges + self loops = 850000
#define NEG_SLOPE 0.2f

// ---------------------------------------------------------------- CSR build
__global__ void k_hist(const int* __restrict__ dstp, int* __restrict__ rowptr) {
    int e = blockIdx.x * blockDim.x + threadIdx.x;
    if (e < TOT_E) {
        int d = (e < N_EDGES) ? dstp[e] : (e - N_EDGES);
        atomicAdd(&rowptr[d + 1], 1);
    }
}

// single-block inclusive scan over rowptr[1..N]; also fills cursor[] = start offsets
__global__ void k_scan(int* __restrict__ rowptr, int* __restrict__ cursor) {
    __shared__ int sh[1024];
    __shared__ int carry_sh;
    int tid = threadIdx.x;
    if (tid == 0) { carry_sh = 0; cursor[0] = 0; }
    __syncthreads();
    for (int base = 0; base < N_NODES; base += 1024) {
        int i = base + tid;
        int v = (i < N_NODES) ? rowptr[i + 1] : 0;
        sh[tid] = v;
        __syncthreads();
        for (int off = 1; off < 1024; off <<= 1) {
            int t = (tid >= off) ? sh[tid - off] : 0;
            __syncthreads();
            sh[tid] += t;
            __syncthreads();
        }
        int carry = carry_sh;
        if (i < N_NODES) {
            int val = carry + sh[tid];
            rowptr[i + 1] = val;
            cursor[i + 1] = val;
        }
        __syncthreads();
        if (tid == 1023) carry_sh = carry + sh[1023];
        __syncthreads();
    }
}

// store SRC node id directly in CSR slot (drops one indirection in k_gat)
__global__ void k_scatter(const int* __restrict__ srcp, const int* __restrict__ dstp,
                          int* __restrict__ cursor, int* __restrict__ esrc) {
    int e = blockIdx.x * blockDim.x + threadIdx.x;
    if (e < TOT_E) {
        int d = (e < N_EDGES) ? dstp[e] : (e - N_EDGES);
        int s = (e < N_EDGES) ? srcp[e] : (e - N_EDGES);
        int pos = atomicAdd(&cursor[d], 1);
        esrc[pos] = s;
    }
}

// ------------------------------------------------- fused dual linear (X@Wa, X@Wb)
__global__ __launch_bounds__(256) void k_linear(const float* __restrict__ X,
                                                const float* __restrict__ Wa,
                                                const float* __restrict__ Wb,
                                                float* __restrict__ outA,
                                                float* __restrict__ outB) {
    __shared__ float xs[8][128];
    int n0 = blockIdx.x * 8;
    int tid = threadIdx.x;
    for (int r = tid; r < 8 * 128; r += 256)
        ((float*)xs)[r] = X[(size_t)n0 * 128 + r];
    __syncthreads();

    int j = tid & 127;
    const float* W = (tid < 128) ? Wa : Wb;
    float* out = (tid < 128) ? outA : outB;
    float acc[8] = {0.f, 0.f, 0.f, 0.f, 0.f, 0.f, 0.f, 0.f};
    for (int k = 0; k < 128; k += 4) {
        float w0 = W[(k + 0) * 128 + j];
        float w1 = W[(k + 1) * 128 + j];
        float w2 = W[(k + 2) * 128 + j];
        float w3 = W[(k + 3) * 128 + j];
#pragma unroll
        for (int nd = 0; nd < 8; ++nd) {
            float4 xv = *(const float4*)&xs[nd][k];
            acc[nd] += xv.x * w0 + xv.y * w1 + xv.z * w2 + xv.w * w3;
        }
    }
#pragma unroll
    for (int nd = 0; nd < 8; ++nd)
        out[(size_t)(n0 + nd) * 128 + j] = acc[nd];
}

// ------------------------------------------------- fused score+softmax+aggregate
// One wave per destination node. Online softmax (running max), exactly one
// __expf per head per edge. xl[src] gathered ONCE per edge, used for both
// score and message. Next edge's row is prefetched to hide gather latency.
// Lane mapping: lane holds elems {lane, 64+lane} (head0/head1 for H=2).
template <int H>
__global__ __launch_bounds__(256) void k_gat(const int* __restrict__ rowptr,
                                             const int* __restrict__ esrc,
                                             const float* __restrict__ xl,
                                             const float* __restrict__ xr,
                                             const float* __restrict__ att,
                                             const float* __restrict__ bias,
                                             float* __restrict__ out) {
    int n = (blockIdx.x * 256 + threadIdx.x) >> 6;
    int lane = threadIdx.x & 63;
    if (n >= N_NODES) return;
    int start = rowptr[n], end = rowptr[n + 1];

    float xr0 = xr[(size_t)n * 128 + lane];
    float xr1 = xr[(size_t)n * 128 + 64 + lane];
    float a0 = att[lane];
    float a1 = att[64 + lane];

    float m0 = -1e30f, m1 = -1e30f;
    float den0 = 0.f, den1 = 0.f;
    float acc0 = 0.f, acc1 = 0.f;

    // prefetch first edge's row (every node has >=1 edge: the self-loop)
    int s = esrc[start];
    float x0 = xl[(size_t)s * 128 + lane];
    float x1 = xl[(size_t)s * 128 + 64 + lane];

    for (int i = start; i < end; ++i) {
        float cx0 = x0, cx1 = x1;
        if (i + 1 < end) {
            int s2 = esrc[i + 1];
            x0 = xl[(size_t)s2 * 128 + lane];
            x1 = xl[(size_t)s2 * 128 + 64 + lane];
        }
        float v0 = cx0 + xr0, v1 = cx1 + xr1;
        v0 = (v0 > 0.f) ? v0 : NEG_SLOPE * v0;
        v1 = (v1 > 0.f) ? v1 : NEG_SLOPE * v1;
        float t0 = v0 * a0, t1 = v1 * a1;

        float sc0, sc1;
        if (H == 1) {
            float t = t0 + t1;
#pragma unroll
            for (int off = 32; off > 0; off >>= 1) t += __shfl_xor(t, off, 64);
            sc0 = t; sc1 = t;
        } else {
#pragma unroll
            for (int off = 32; off > 0; off >>= 1) t0 += __shfl_xor(t0, off, 64);
#pragma unroll
            for (int off = 32; off > 0; off >>= 1) t1 += __shfl_xor(t1, off, 64);
            sc0 = t0; sc1 = t1;
        }

        // online softmax, head 0
        float corr0, p0;
        if (sc0 > m0) { corr0 = __expf(m0 - sc0); p0 = 1.f; m0 = sc0; }
        else          { corr0 = 1.f; p0 = __expf(sc0 - m0); }
        den0 = den0 * corr0 + p0;
        acc0 = acc0 * corr0 + p0 * cx0;

        // head 1 (H=1: same scalar score -> reuse p/corr)
        float corr1, p1;
        if (H == 1) { corr1 = corr0; p1 = p0; }
        else {
            if (sc1 > m1) { corr1 = __expf(m1 - sc1); p1 = 1.f; m1 = sc1; }
            else          { corr1 = 1.f; p1 = __expf(sc1 - m1); }
        }
        den1 = den1 * corr1 + p1;
        acc1 = acc1 * corr1 + p1 * cx1;
    }

    float o0 = acc0 / (den0 + 1e-16f) + bias[lane];
    float o1 = acc1 / (den1 + 1e-16f) + bias[64 + lane];
    o0 = (o0 > 0.f) ? o0 : (__expf(o0) - 1.f);   // ELU
    o1 = (o1 > 0.f) ? o1 : (__expf(o1) - 1.f);
    out[(size_t)n * 128 + lane] = o0;
    out[(size_t)n * 128 + 64 + lane] = o1;
}

// ---------------------------------------------------------------- launch
extern "C" void kernel_launch(void* const* d_in, const int* in_sizes, int n_in,
                              void* d_out, int out_size, void* d_ws, size_t ws_size,
                              hipStream_t stream) {
    const float* x    = (const float*)d_in[0];
    const int*   ei   = (const int*)d_in[1];
    const float* Wl1  = (const float*)d_in[2];
    const float* Wr1  = (const float*)d_in[3];
    const float* att1 = (const float*)d_in[4];
    const float* b1   = (const float*)d_in[5];
    const float* Wl2  = (const float*)d_in[6];
    const float* Wr2  = (const float*)d_in[7];
    const float* att2 = (const float*)d_in[8];
    const float* b2   = (const float*)d_in[9];
    const int* srcp = ei;
    const int* dstp = ei + N_EDGES;

    char* ws = (char*)d_ws;
    size_t off = 0;
    auto alloc = [&](size_t bytes) {
        void* p = ws + off;
        off = (off + bytes + 255) & ~(size_t)255;
        return p;
    };
    int*   rowptr = (int*)alloc((N_NODES + 1) * sizeof(int));
    int*   cursor = (int*)alloc((N_NODES + 1) * sizeof(int));
    int*   esrc   = (int*)alloc((size_t)TOT_E * sizeof(int));
    float* xl     = (float*)alloc((size_t)N_NODES * 128 * sizeof(float));
    float* xr     = (float*)alloc((size_t)N_NODES * 128 * sizeof(float));
    float* h1     = (float*)alloc((size_t)N_NODES * 128 * sizeof(float));

    // CSR build (graph is identical for both layers)
    hipMemsetAsync(rowptr, 0, (N_NODES + 1) * sizeof(int), stream);
    k_hist<<<(TOT_E + 255) / 256, 256, 0, stream>>>(dstp, rowptr);
    k_scan<<<1, 1024, 0, stream>>>(rowptr, cursor);
    k_scatter<<<(TOT_E + 255) / 256, 256, 0, stream>>>(srcp, dstp, cursor, esrc);

    // layer 1: heads=2, C=64, concat
    k_linear<<<N_NODES / 8, 256, 0, stream>>>(x, Wl1, Wr1, xl, xr);
    k_gat<2><<<(N_NODES + 3) / 4, 256, 0, stream>>>(rowptr, esrc, xl, xr, att1, b1, h1);

    // layer 2: heads=1, C=128, mean over 1 head = identity
    k_linear<<<N_NODES / 8, 256, 0, stream>>>(h1, Wl2, Wr2, xl, xr);
    k_gat<1><<<(N_NODES + 3) / 4, 256, 0, stream>>>(rowptr, esrc, xl, xr, att2, b2, (float*)d_out);
}

// Round 3
// 431.009 us; speedup vs baseline: 2.2883x; 1.4113x over previous
//
#include <hip/hip_runtime.h>
#include <hip/hip_bf16.h>

#define N_NODES 50000
#define N_EDGES 800000
#define TOT_E   (N_EDGES + N_NODES)   // edges + self loops = 850000
#define NEG_SLOPE 0.2f
#define SCAN_B 1024
#define NBLK ((N_NODES + SCAN_B - 1) / SCAN_B)   // 49

// ---------------------------------------------------------------- CSR build
__global__ void k_hist(const int* __restrict__ dstp, int* __restrict__ rowptr) {
    int e = blockIdx.x * blockDim.x + threadIdx.x;
    if (e < TOT_E) {
        int d = (e < N_EDGES) ? dstp[e] : (e - N_EDGES);
        atomicAdd(&rowptr[d + 1], 1);
    }
}

// multi-block scan, phase A: per-block inclusive scan of degrees
__global__ __launch_bounds__(SCAN_B) void k_scan_a(int* __restrict__ rowptr,
                                                   int* __restrict__ bsum) {
    __shared__ int sh[SCAN_B];
    int t = threadIdx.x;
    int i = blockIdx.x * SCAN_B + t;
    int v = (i < N_NODES) ? rowptr[i + 1] : 0;
    sh[t] = v;
    __syncthreads();
    for (int off = 1; off < SCAN_B; off <<= 1) {
        int u = (t >= off) ? sh[t - off] : 0;
        __syncthreads();
        sh[t] += u;
        __syncthreads();
    }
    if (i < N_NODES) rowptr[i + 1] = sh[t];
    if (t == SCAN_B - 1) bsum[blockIdx.x] = sh[t];
}

// phase B: one wave scans the 49 block sums -> exclusive offsets
__global__ void k_scan_b(const int* __restrict__ bsum, int* __restrict__ boffs) {
    int t = threadIdx.x;   // 64 threads
    int own = (t < NBLK) ? bsum[t] : 0;
    int v = own;
#pragma unroll
    for (int off = 1; off < 64; off <<= 1) {
        int u = __shfl_up(v, off, 64);
        if (t >= off) v += u;
    }
    if (t < NBLK) boffs[t] = v - own;
}

// phase C: add block offsets, fill cursor
__global__ void k_scan_c(int* __restrict__ rowptr, const int* __restrict__ boffs,
                         int* __restrict__ cursor) {
    int i = blockIdx.x * 256 + threadIdx.x;
    if (i < N_NODES) {
        int val = rowptr[i + 1] + boffs[i >> 10];
        rowptr[i + 1] = val;
        cursor[i + 1] = val;
    }
    if (i == 0) { rowptr[0] = 0; cursor[0] = 0; }
}

// store SRC node id directly in CSR slot
__global__ void k_scatter(const int* __restrict__ srcp, const int* __restrict__ dstp,
                          int* __restrict__ cursor, int* __restrict__ esrc) {
    int e = blockIdx.x * blockDim.x + threadIdx.x;
    if (e < TOT_E) {
        int d = (e < N_EDGES) ? dstp[e] : (e - N_EDGES);
        int s = (e < N_EDGES) ? srcp[e] : (e - N_EDGES);
        int pos = atomicAdd(&cursor[d], 1);
        esrc[pos] = s;
    }
}

// ------------------------------------------------- fused dual linear (X@Wa, X@Wb)
__global__ __launch_bounds__(256) void k_linear(const float* __restrict__ X,
                                                const float* __restrict__ Wa,
                                                const float* __restrict__ Wb,
                                                float* __restrict__ outA,
                                                float* __restrict__ outB) {
    __shared__ float xs[8][128];
    int n0 = blockIdx.x * 8;
    int tid = threadIdx.x;
    for (int r = tid; r < 8 * 128; r += 256)
        ((float*)xs)[r] = X[(size_t)n0 * 128 + r];
    __syncthreads();

    int j = tid & 127;
    const float* W = (tid < 128) ? Wa : Wb;
    float* out = (tid < 128) ? outA : outB;
    float acc[8] = {0.f, 0.f, 0.f, 0.f, 0.f, 0.f, 0.f, 0.f};
    for (int k = 0; k < 128; k += 4) {
        float w0 = W[(k + 0) * 128 + j];
        float w1 = W[(k + 1) * 128 + j];
        float w2 = W[(k + 2) * 128 + j];
        float w3 = W[(k + 3) * 128 + j];
#pragma unroll
        for (int nd = 0; nd < 8; ++nd) {
            float4 xv = *(const float4*)&xs[nd][k];
            acc[nd] = fmaf(xv.x, w0, acc[nd]);
            acc[nd] = fmaf(xv.y, w1, acc[nd]);
            acc[nd] = fmaf(xv.z, w2, acc[nd]);
            acc[nd] = fmaf(xv.w, w3, acc[nd]);
        }
    }
#pragma unroll
    for (int nd = 0; nd < 8; ++nd)
        out[(size_t)(n0 + nd) * 128 + j] = acc[nd];
}

// ------------------------------------------------- fused score+softmax+aggregate
// One wave per destination node; lane l owns elems {2l, 2l+1} (float2).
// H=2: elems 2l,2l+1 are in head l>>5, and the head score is the 32-lane
// half-sum -> 5 shfl_xor, all online-softmax state per-lane, branchless.
// H=1: full 64-lane sum (6 shfl_xor). 2-edge unroll: score chains interleave.
template <int H>
__global__ __launch_bounds__(256) void k_gat(const int* __restrict__ rowptr,
                                             const int* __restrict__ esrc,
                                             const float* __restrict__ xl,
                                             const float* __restrict__ xr,
                                             const float* __restrict__ att,
                                             const float* __restrict__ bias,
                                             float* __restrict__ out) {
    int n = (blockIdx.x * 256 + threadIdx.x) >> 6;
    int lane = threadIdx.x & 63;
    if (n >= N_NODES) return;
    int start = rowptr[n], end = rowptr[n + 1];

    float2 xr2 = *(const float2*)&xr[(size_t)n * 128 + 2 * lane];
    float2 a2  = *(const float2*)&att[2 * lane];
    float2 bb  = *(const float2*)&bias[2 * lane];

    float m = -1e30f, den = 0.f, accx = 0.f, accy = 0.f;

    auto lane_t = [&](float2 c) {
        float v0 = c.x + xr2.x, v1 = c.y + xr2.y;
        v0 = (v0 > 0.f) ? v0 : NEG_SLOPE * v0;
        v1 = (v1 > 0.f) ? v1 : NEG_SLOPE * v1;
        return fmaf(v0, a2.x, v1 * a2.y);
    };
    auto update = [&](float sc, float2 c) {
        float mn = fmaxf(m, sc);
        float corr = __expf(m - mn);
        float p = __expf(sc - mn);
        m = mn;
        den = fmaf(den, corr, p);
        accx = fmaf(accx, corr, p * c.x);
        accy = fmaf(accy, corr, p * c.y);
    };

    // prefetch up to 2 rows (every node has >=1 edge: self-loop)
    int s0 = esrc[start];
    float2 r0 = *(const float2*)&xl[(size_t)s0 * 128 + 2 * lane];
    float2 r1 = r0;
    if (start + 1 < end) {
        int s1 = esrc[start + 1];
        r1 = *(const float2*)&xl[(size_t)s1 * 128 + 2 * lane];
    }

    int i = start;
    for (; i + 1 < end; i += 2) {
        float2 c0 = r0, c1 = r1;
        if (i + 2 < end) {
            int sa = esrc[i + 2];
            r0 = *(const float2*)&xl[(size_t)sa * 128 + 2 * lane];
        }
        if (i + 3 < end) {
            int sb = esrc[i + 3];
            r1 = *(const float2*)&xl[(size_t)sb * 128 + 2 * lane];
        }
        float t0 = lane_t(c0);
        float t1 = lane_t(c1);
        const int TOP = (H == 2) ? 16 : 32;   // half-sum vs full-sum
#pragma unroll
        for (int off = 1; off <= TOP; off <<= 1) {
            float u0 = __shfl_xor(t0, off, 64);
            float u1 = __shfl_xor(t1, off, 64);
            t0 += u0;
            t1 += u1;
        }
        update(t0, c0);
        update(t1, c1);
    }
    if (i < end) {   // odd tail
        float2 c0 = r0;
        float t0 = lane_t(c0);
        const int TOP = (H == 2) ? 16 : 32;
#pragma unroll
        for (int off = 1; off <= TOP; off <<= 1)
            t0 += __shfl_xor(t0, off, 64);
        update(t0, c0);
    }

    float inv = 1.f / (den + 1e-16f);
    float o0 = fmaf(accx, inv, bb.x);
    float o1 = fmaf(accy, inv, bb.y);
    o0 = (o0 > 0.f) ? o0 : (__expf(o0) - 1.f);   // ELU
    o1 = (o1 > 0.f) ? o1 : (__expf(o1) - 1.f);
    *(float2*)&out[(size_t)n * 128 + 2 * lane] = make_float2(o0, o1);
}

// ---------------------------------------------------------------- launch
extern "C" void kernel_launch(void* const* d_in, const int* in_sizes, int n_in,
                              void* d_out, int out_size, void* d_ws, size_t ws_size,
                              hipStream_t stream) {
    const float* x    = (const float*)d_in[0];
    const int*   ei   = (const int*)d_in[1];
    const float* Wl1  = (const float*)d_in[2];
    const float* Wr1  = (const float*)d_in[3];
    const float* att1 = (const float*)d_in[4];
    const float* b1   = (const float*)d_in[5];
    const float* Wl2  = (const float*)d_in[6];
    const float* Wr2  = (const float*)d_in[7];
    const float* att2 = (const float*)d_in[8];
    const float* b2   = (const float*)d_in[9];
    const int* srcp = ei;
    const int* dstp = ei + N_EDGES;

    char* ws = (char*)d_ws;
    size_t off = 0;
    auto alloc = [&](size_t bytes) {
        void* p = ws + off;
        off = (off + bytes + 255) & ~(size_t)255;
        return p;
    };
    int*   rowptr = (int*)alloc((N_NODES + 1) * sizeof(int));
    int*   cursor = (int*)alloc((N_NODES + 1) * sizeof(int));
    int*   esrc   = (int*)alloc((size_t)TOT_E * sizeof(int));
    int*   bsum   = (int*)alloc(NBLK * sizeof(int));
    int*   boffs  = (int*)alloc(NBLK * sizeof(int));
    float* xl     = (float*)alloc((size_t)N_NODES * 128 * sizeof(float));
    float* xr     = (float*)alloc((size_t)N_NODES * 128 * sizeof(float));
    float* h1     = (float*)alloc((size_t)N_NODES * 128 * sizeof(float));

    // CSR build (graph is identical for both layers)
    hipMemsetAsync(rowptr, 0, (N_NODES + 1) * sizeof(int), stream);
    k_hist<<<(TOT_E + 255) / 256, 256, 0, stream>>>(dstp, rowptr);
    k_scan_a<<<NBLK, SCAN_B, 0, stream>>>(rowptr, bsum);
    k_scan_b<<<1, 64, 0, stream>>>(bsum, boffs);
    k_scan_c<<<(N_NODES + 255) / 256, 256, 0, stream>>>(rowptr, boffs, cursor);
    k_scatter<<<(TOT_E + 255) / 256, 256, 0, stream>>>(srcp, dstp, cursor, esrc);

    // layer 1: heads=2, C=64, concat
    k_linear<<<N_NODES / 8, 256, 0, stream>>>(x, Wl1, Wr1, xl, xr);
    k_gat<2><<<(N_NODES + 3) / 4, 256, 0, stream>>>(rowptr, esrc, xl, xr, att1, b1, h1);

    // layer 2: heads=1, C=128, mean over 1 head = identity
    k_linear<<<N_NODES / 8, 256, 0, stream>>>(h1, Wl2, Wr2, xl, xr);
    k_gat<1><<<(N_NODES + 3) / 4, 256, 0, stream>>>(rowptr, esrc, xl, xr, att2, b2, (float*)d_out);
}

// Round 4
// 411.910 us; speedup vs baseline: 2.3944x; 1.0464x over previous
//
#include <hip/hip_runtime.h>
#include <hip/hip_bf16.h>

#define N_NODES 50000
#define N_EDGES 800000
#define TOT_E   (N_EDGES + N_NODES)   // edges + self loops = 850000
#define NEG_SLOPE 0.2f
#define SCAN_B 1024
#define NBLK ((N_NODES + SCAN_B - 1) / SCAN_B)   // 49
#define LIN_NODES 32

// ---------------------------------------------------------------- CSR build
__global__ void k_hist(const int* __restrict__ dstp, int* __restrict__ rowptr) {
    int e = blockIdx.x * blockDim.x + threadIdx.x;
    if (e < TOT_E) {
        int d = (e < N_EDGES) ? dstp[e] : (e - N_EDGES);
        atomicAdd(&rowptr[d + 1], 1);
    }
}

__global__ __launch_bounds__(SCAN_B) void k_scan_a(int* __restrict__ rowptr,
                                                   int* __restrict__ bsum) {
    __shared__ int sh[SCAN_B];
    int t = threadIdx.x;
    int i = blockIdx.x * SCAN_B + t;
    int v = (i < N_NODES) ? rowptr[i + 1] : 0;
    sh[t] = v;
    __syncthreads();
    for (int off = 1; off < SCAN_B; off <<= 1) {
        int u = (t >= off) ? sh[t - off] : 0;
        __syncthreads();
        sh[t] += u;
        __syncthreads();
    }
    if (i < N_NODES) rowptr[i + 1] = sh[t];
    if (t == SCAN_B - 1) bsum[blockIdx.x] = sh[t];
}

__global__ void k_scan_b(const int* __restrict__ bsum, int* __restrict__ boffs) {
    int t = threadIdx.x;   // 64 threads
    int own = (t < NBLK) ? bsum[t] : 0;
    int v = own;
#pragma unroll
    for (int off = 1; off < 64; off <<= 1) {
        int u = __shfl_up(v, off, 64);
        if (t >= off) v += u;
    }
    if (t < NBLK) boffs[t] = v - own;
}

__global__ void k_scan_c(int* __restrict__ rowptr, const int* __restrict__ boffs,
                         int* __restrict__ cursor) {
    int i = blockIdx.x * 256 + threadIdx.x;
    if (i < N_NODES) {
        int val = rowptr[i + 1] + boffs[i >> 10];
        rowptr[i + 1] = val;
        cursor[i + 1] = val;
    }
    if (i == 0) { rowptr[0] = 0; cursor[0] = 0; }
}

__global__ void k_scatter(const int* __restrict__ srcp, const int* __restrict__ dstp,
                          int* __restrict__ cursor, int* __restrict__ esrc) {
    int e = blockIdx.x * blockDim.x + threadIdx.x;
    if (e < TOT_E) {
        int d = (e < N_EDGES) ? dstp[e] : (e - N_EDGES);
        int s = (e < N_EDGES) ? srcp[e] : (e - N_EDGES);
        int pos = atomicAdd(&cursor[d], 1);
        esrc[pos] = s;
    }
}

// ------------------------------------------------- fused dual linear (X@Wa, X@Wb)
// 32 nodes/block, 256 threads. Thread t: j = t&127, grp = t>>7 -> nodes
// grp*16 .. grp*16+15. Each thread computes BOTH Wa and Wb columns for its
// 16 nodes: per 4-k step = 16 ds_read_b128 + 8 W loads + 128 FMA (VALU-bound
// ~75%; W L2 traffic amortized over 32 nodes).
__global__ __launch_bounds__(256) void k_linear(const float* __restrict__ X,
                                                const float* __restrict__ Wa,
                                                const float* __restrict__ Wb,
                                                float* __restrict__ outA,
                                                float* __restrict__ outB,
                                                int n_nodes) {
    __shared__ float xs[LIN_NODES][128];
    int n0 = blockIdx.x * LIN_NODES;
    int tid = threadIdx.x;
    for (int r = tid; r < LIN_NODES * 32; r += 256) {
        int row = r >> 5;
        int c4 = (r & 31) << 2;
        float4 v = make_float4(0.f, 0.f, 0.f, 0.f);
        if (n0 + row < n_nodes) v = *(const float4*)&X[(size_t)(n0 + row) * 128 + c4];
        *(float4*)&xs[row][c4] = v;
    }
    __syncthreads();

    int j = tid & 127;
    int nb = (tid >> 7) * 16;
    float accA[16] = {0.f, 0.f, 0.f, 0.f, 0.f, 0.f, 0.f, 0.f,
                      0.f, 0.f, 0.f, 0.f, 0.f, 0.f, 0.f, 0.f};
    float accB[16] = {0.f, 0.f, 0.f, 0.f, 0.f, 0.f, 0.f, 0.f,
                      0.f, 0.f, 0.f, 0.f, 0.f, 0.f, 0.f, 0.f};
    for (int k = 0; k < 128; k += 4) {
        float wa0 = Wa[(k + 0) * 128 + j];
        float wa1 = Wa[(k + 1) * 128 + j];
        float wa2 = Wa[(k + 2) * 128 + j];
        float wa3 = Wa[(k + 3) * 128 + j];
        float wb0 = Wb[(k + 0) * 128 + j];
        float wb1 = Wb[(k + 1) * 128 + j];
        float wb2 = Wb[(k + 2) * 128 + j];
        float wb3 = Wb[(k + 3) * 128 + j];
#pragma unroll
        for (int nd = 0; nd < 16; ++nd) {
            float4 xv = *(const float4*)&xs[nb + nd][k];
            accA[nd] = fmaf(xv.x, wa0, accA[nd]);
            accA[nd] = fmaf(xv.y, wa1, accA[nd]);
            accA[nd] = fmaf(xv.z, wa2, accA[nd]);
            accA[nd] = fmaf(xv.w, wa3, accA[nd]);
            accB[nd] = fmaf(xv.x, wb0, accB[nd]);
            accB[nd] = fmaf(xv.y, wb1, accB[nd]);
            accB[nd] = fmaf(xv.z, wb2, accB[nd]);
            accB[nd] = fmaf(xv.w, wb3, accB[nd]);
        }
    }
#pragma unroll
    for (int nd = 0; nd < 16; ++nd) {
        int n = n0 + nb + nd;
        if (n < n_nodes) {
            outA[(size_t)n * 128 + j] = accA[nd];
            outB[(size_t)n * 128 + j] = accB[nd];
        }
    }
}

// ------------------------------------------------- fused score+softmax+aggregate
// One wave per destination node; lane l owns elems {2l, 2l+1} (float2).
// H=2: elems 2l,2l+1 are in head l>>5, head score = 32-lane half-sum ->
// 5 shfl_xor; online-softmax state per-lane, branchless. H=1: 6 shfl_xor.
// 2-edge unroll: score shuffle chains interleave; prefetch distance 2.
template <int H>
__global__ __launch_bounds__(256) void k_gat(const int* __restrict__ rowptr,
                                             const int* __restrict__ esrc,
                                             const float* __restrict__ xl,
                                             const float* __restrict__ xr,
                                             const float* __restrict__ att,
                                             const float* __restrict__ bias,
                                             float* __restrict__ out) {
    int n = (blockIdx.x * 256 + threadIdx.x) >> 6;
    int lane = threadIdx.x & 63;
    if (n >= N_NODES) return;
    int start = rowptr[n], end = rowptr[n + 1];

    float2 xr2 = *(const float2*)&xr[(size_t)n * 128 + 2 * lane];
    float2 a2  = *(const float2*)&att[2 * lane];
    float2 bb  = *(const float2*)&bias[2 * lane];

    float m = -1e30f, den = 0.f, accx = 0.f, accy = 0.f;

    auto lane_t = [&](float2 c) {
        float v0 = c.x + xr2.x, v1 = c.y + xr2.y;
        v0 = (v0 > 0.f) ? v0 : NEG_SLOPE * v0;
        v1 = (v1 > 0.f) ? v1 : NEG_SLOPE * v1;
        return fmaf(v0, a2.x, v1 * a2.y);
    };
    auto update = [&](float sc, float2 c) {
        float mn = fmaxf(m, sc);
        float corr = __expf(m - mn);
        float p = __expf(sc - mn);
        m = mn;
        den = fmaf(den, corr, p);
        accx = fmaf(accx, corr, p * c.x);
        accy = fmaf(accy, corr, p * c.y);
    };

    int s0 = esrc[start];
    float2 r0 = *(const float2*)&xl[(size_t)s0 * 128 + 2 * lane];
    float2 r1 = r0;
    if (start + 1 < end) {
        int s1 = esrc[start + 1];
        r1 = *(const float2*)&xl[(size_t)s1 * 128 + 2 * lane];
    }

    int i = start;
    for (; i + 1 < end; i += 2) {
        float2 c0 = r0, c1 = r1;
        if (i + 2 < end) {
            int sa = esrc[i + 2];
            r0 = *(const float2*)&xl[(size_t)sa * 128 + 2 * lane];
        }
        if (i + 3 < end) {
            int sb = esrc[i + 3];
            r1 = *(const float2*)&xl[(size_t)sb * 128 + 2 * lane];
        }
        float t0 = lane_t(c0);
        float t1 = lane_t(c1);
        const int TOP = (H == 2) ? 16 : 32;
#pragma unroll
        for (int off = 1; off <= TOP; off <<= 1) {
            float u0 = __shfl_xor(t0, off, 64);
            float u1 = __shfl_xor(t1, off, 64);
            t0 += u0;
            t1 += u1;
        }
        update(t0, c0);
        update(t1, c1);
    }
    if (i < end) {
        float2 c0 = r0;
        float t0 = lane_t(c0);
        const int TOP = (H == 2) ? 16 : 32;
#pragma unroll
        for (int off = 1; off <= TOP; off <<= 1)
            t0 += __shfl_xor(t0, off, 64);
        update(t0, c0);
    }

    float inv = 1.f / (den + 1e-16f);
    float o0 = fmaf(accx, inv, bb.x);
    float o1 = fmaf(accy, inv, bb.y);
    o0 = (o0 > 0.f) ? o0 : (__expf(o0) - 1.f);   // ELU
    o1 = (o1 > 0.f) ? o1 : (__expf(o1) - 1.f);
    *(float2*)&out[(size_t)n * 128 + 2 * lane] = make_float2(o0, o1);
}

// ---------------------------------------------------------------- launch
extern "C" void kernel_launch(void* const* d_in, const int* in_sizes, int n_in,
                              void* d_out, int out_size, void* d_ws, size_t ws_size,
                              hipStream_t stream) {
    const float* x    = (const float*)d_in[0];
    const int*   ei   = (const int*)d_in[1];
    const float* Wl1  = (const float*)d_in[2];
    const float* Wr1  = (const float*)d_in[3];
    const float* att1 = (const float*)d_in[4];
    const float* b1   = (const float*)d_in[5];
    const float* Wl2  = (const float*)d_in[6];
    const float* Wr2  = (const float*)d_in[7];
    const float* att2 = (const float*)d_in[8];
    const float* b2   = (const float*)d_in[9];
    const int* srcp = ei;
    const int* dstp = ei + N_EDGES;

    char* ws = (char*)d_ws;
    size_t off = 0;
    auto alloc = [&](size_t bytes) {
        void* p = ws + off;
        off = (off + bytes + 255) & ~(size_t)255;
        return p;
    };
    int*   rowptr = (int*)alloc((N_NODES + 1) * sizeof(int));
    int*   cursor = (int*)alloc((N_NODES + 1) * sizeof(int));
    int*   esrc   = (int*)alloc((size_t)TOT_E * sizeof(int));
    int*   bsum   = (int*)alloc(NBLK * sizeof(int));
    int*   boffs  = (int*)alloc(NBLK * sizeof(int));
    float* xl     = (float*)alloc((size_t)N_NODES * 128 * sizeof(float));
    float* xr     = (float*)alloc((size_t)N_NODES * 128 * sizeof(float));
    float* h1     = (float*)alloc((size_t)N_NODES * 128 * sizeof(float));

    // CSR build (graph is identical for both layers)
    hipMemsetAsync(rowptr, 0, (N_NODES + 1) * sizeof(int), stream);
    k_hist<<<(TOT_E + 255) / 256, 256, 0, stream>>>(dstp, rowptr);
    k_scan_a<<<NBLK, SCAN_B, 0, stream>>>(rowptr, bsum);
    k_scan_b<<<1, 64, 0, stream>>>(bsum, boffs);
    k_scan_c<<<(N_NODES + 255) / 256, 256, 0, stream>>>(rowptr, boffs, cursor);
    k_scatter<<<(TOT_E + 255) / 256, 256, 0, stream>>>(srcp, dstp, cursor, esrc);

    int lin_grid = (N_NODES + LIN_NODES - 1) / LIN_NODES;

    // layer 1: heads=2, C=64, concat
    k_linear<<<lin_grid, 256, 0, stream>>>(x, Wl1, Wr1, xl, xr, N_NODES);
    k_gat<2><<<(N_NODES + 3) / 4, 256, 0, stream>>>(rowptr, esrc, xl, xr, att1, b1, h1);

    // layer 2: heads=1, C=128, mean over 1 head = identity
    k_linear<<<lin_grid, 256, 0, stream>>>(h1, Wl2, Wr2, xl, xr, N_NODES);
    k_gat<1><<<(N_NODES + 3) / 4, 256, 0, stream>>>(rowptr, esrc, xl, xr, att2, b2, (float*)d_out);
}

// Round 5
// 344.607 us; speedup vs baseline: 2.8620x; 1.1953x over previous
//
#include <hip/hip_runtime.h>
#include <hip/hip_bf16.h>

#define N_NODES 50000
#define N_EDGES 800000
#define TOT_E   (N_EDGES + N_NODES)   // edges + self loops = 850000
#define NEG_SLOPE 0.2f
#define SCAN_B 1024
#define NBLK ((N_NODES + SCAN_B - 1) / SCAN_B)   // 49

typedef __attribute__((ext_vector_type(8))) short bf16x8;
typedef __attribute__((ext_vector_type(4))) float f32x4;

static __device__ __forceinline__ unsigned short f2bf(float f) {
    unsigned int u = __float_as_uint(f);
    unsigned int r = (u + 0x7FFFu + ((u >> 16) & 1u)) >> 16;   // RNE
    return (unsigned short)r;
}
static __device__ __forceinline__ float bf2f(unsigned short h) {
    return __uint_as_float(((unsigned int)h) << 16);
}

// ---------------------------------------------------------------- CSR build
__global__ void k_hist(const int* __restrict__ dstp, int* __restrict__ rowptr) {
    int e = blockIdx.x * blockDim.x + threadIdx.x;
    if (e < TOT_E) {
        int d = (e < N_EDGES) ? dstp[e] : (e - N_EDGES);
        atomicAdd(&rowptr[d + 1], 1);
    }
}

__global__ __launch_bounds__(SCAN_B) void k_scan_a(int* __restrict__ rowptr,
                                                   int* __restrict__ bsum) {
    __shared__ int sh[SCAN_B];
    int t = threadIdx.x;
    int i = blockIdx.x * SCAN_B + t;
    int v = (i < N_NODES) ? rowptr[i + 1] : 0;
    sh[t] = v;
    __syncthreads();
    for (int off = 1; off < SCAN_B; off <<= 1) {
        int u = (t >= off) ? sh[t - off] : 0;
        __syncthreads();
        sh[t] += u;
        __syncthreads();
    }
    if (i < N_NODES) rowptr[i + 1] = sh[t];
    if (t == SCAN_B - 1) bsum[blockIdx.x] = sh[t];
}

__global__ void k_scan_b(const int* __restrict__ bsum, int* __restrict__ boffs) {
    int t = threadIdx.x;   // 64 threads
    int own = (t < NBLK) ? bsum[t] : 0;
    int v = own;
#pragma unroll
    for (int off = 1; off < 64; off <<= 1) {
        int u = __shfl_up(v, off, 64);
        if (t >= off) v += u;
    }
    if (t < NBLK) boffs[t] = v - own;
}

__global__ void k_scan_c(int* __restrict__ rowptr, const int* __restrict__ boffs,
                         int* __restrict__ cursor) {
    int i = blockIdx.x * 256 + threadIdx.x;
    if (i < N_NODES) {
        int val = rowptr[i + 1] + boffs[i >> 10];
        rowptr[i + 1] = val;
        cursor[i + 1] = val;
    }
    if (i == 0) { rowptr[0] = 0; cursor[0] = 0; }
}

__global__ void k_scatter(const int* __restrict__ srcp, const int* __restrict__ dstp,
                          int* __restrict__ cursor, int* __restrict__ esrc) {
    int e = blockIdx.x * blockDim.x + threadIdx.x;
    if (e < TOT_E) {
        int d = (e < N_EDGES) ? dstp[e] : (e - N_EDGES);
        int s = (e < N_EDGES) ? srcp[e] : (e - N_EDGES);
        int pos = atomicAdd(&cursor[d], 1);
        esrc[pos] = s;
    }
}

// ------------------------------------------------- f32 -> (hi|lo) bf16 split
// Ap[row][0..127] = bf16_hi(x), Ap[row][128..255] = bf16(x - hi)
__global__ void k_split(const float* __restrict__ X, unsigned short* __restrict__ Ap) {
    int t = blockIdx.x * 256 + threadIdx.x;   // one float4 per thread
    if (t >= N_NODES * 32) return;
    int row = t >> 5, c4 = (t & 31) * 4;
    float4 v = *(const float4*)&X[(size_t)row * 128 + c4];
    float vv[4] = {v.x, v.y, v.z, v.w};
    ushort4 hh, ll;
    unsigned short* hp = &hh.x;
    unsigned short* lp = &ll.x;
#pragma unroll
    for (int i = 0; i < 4; ++i) {
        unsigned short h = f2bf(vv[i]);
        hp[i] = h;
        lp[i] = f2bf(vv[i] - bf2f(h));
    }
    *(ushort4*)&Ap[(size_t)row * 256 + c4] = hh;
    *(ushort4*)&Ap[(size_t)row * 256 + 128 + c4] = ll;
}

// ------------------------------------------------- weight pack -> MFMA frag order
// B' is [K'=256][N=256]: cols 0-127 = Wa, 128-255 = Wb; rows k and k+128 identical
// (hi/lo K-split shares W). Packed so each wave frag load is 1KB coalesced:
// Bp[((ks*16+ctg)*64+lane)*8+j] = B'[ks*32+(lane>>4)*8+j][ctg*16+(lane&15)]
__global__ void k_pack(const float* __restrict__ Wa, const float* __restrict__ Wb,
                       unsigned short* __restrict__ Bp) {
    int idx = blockIdx.x * 256 + threadIdx.x;   // 65536 total
    int j = idx & 7, lane = (idx >> 3) & 63, t = idx >> 9;
    int ks = t >> 4, ctg = t & 15;
    int k = (ks * 32 + (lane >> 4) * 8 + j) & 127;
    int n = ctg * 16 + (lane & 15);
    float v = (n < 128) ? Wa[k * 128 + n] : Wb[k * 128 + (n - 128)];
    Bp[idx] = f2bf(v);
}

// ------------------------------------------------- MFMA dual linear
// C = A' @ B' : A' = [hi|lo] bf16 [M][256], out cols 0-127 -> outA, 128-255 -> outB.
// 64 rows/block, 4 waves x 64-col strip, whole K'=256 in one LDS tile.
__global__ __launch_bounds__(256) void k_mfma_lin(const unsigned short* __restrict__ Ap,
                                                  const unsigned short* __restrict__ Bp,
                                                  float* __restrict__ outA,
                                                  float* __restrict__ outB, int M) {
    __shared__ unsigned short lds_a[64][264];   // +8 pad: 2-way (free) bank access
    int tid = threadIdx.x;
    int n0 = blockIdx.x * 64;
#pragma unroll
    for (int r = 0; r < 8; ++r) {
        int c = r * 256 + tid;          // 16B-chunk id, 2048 total
        int row = c >> 5;
        int col = (c & 31) * 8;
        int gr = n0 + row;
        if (gr >= M) gr = M - 1;
        float4 v = *(const float4*)&Ap[(size_t)gr * 256 + col];
        *(float4*)&lds_a[row][col] = v;
    }
    __syncthreads();

    int w = tid >> 6, lane = tid & 63;
    int lrow = lane & 15, lhi = lane >> 4;
    f32x4 acc[4][4] = {};   // [mt][ct]
    const bf16x8* Bf = (const bf16x8*)Bp;
#pragma unroll
    for (int ks = 0; ks < 8; ++ks) {
        bf16x8 bfr[4], afr[4];
#pragma unroll
        for (int ct = 0; ct < 4; ++ct)
            bfr[ct] = Bf[(ks * 16 + (w * 4 + ct)) * 64 + lane];
#pragma unroll
        for (int mt = 0; mt < 4; ++mt)
            afr[mt] = *(const bf16x8*)&lds_a[mt * 16 + lrow][ks * 32 + lhi * 8];
#pragma unroll
        for (int mt = 0; mt < 4; ++mt)
#pragma unroll
            for (int ct = 0; ct < 4; ++ct)
                acc[mt][ct] = __builtin_amdgcn_mfma_f32_16x16x32_bf16(
                    afr[mt], bfr[ct], acc[mt][ct], 0, 0, 0);
    }
#pragma unroll
    for (int mt = 0; mt < 4; ++mt) {
        int row0 = n0 + mt * 16 + lhi * 4;
#pragma unroll
        for (int ct = 0; ct < 4; ++ct) {
            int col = w * 64 + ct * 16 + lrow;     // wave-uniform branch below
            float* dst = (col < 128) ? outA : outB;
            int cc = col & 127;
#pragma unroll
            for (int reg = 0; reg < 4; ++reg) {
                int rg = row0 + reg;
                if (rg < M) dst[(size_t)rg * 128 + cc] = acc[mt][ct][reg];
            }
        }
    }
}

// ------------------------------------------------- fused score+softmax+aggregate
// One wave per destination node; lane l owns elems {2l, 2l+1} (float2).
// H=2: head score = 32-lane half-sum -> 5 shfl_xor; per-lane online softmax.
// BF16OUT: epilogue writes hi/lo bf16 split (layer-2 GEMM A operand).
template <int H, bool BF16OUT>
__global__ __launch_bounds__(256) void k_gat(const int* __restrict__ rowptr,
                                             const int* __restrict__ esrc,
                                             const float* __restrict__ xl,
                                             const float* __restrict__ xr,
                                             const float* __restrict__ att,
                                             const float* __restrict__ bias,
                                             float* __restrict__ out,
                                             unsigned short* __restrict__ outb) {
    int n = (blockIdx.x * 256 + threadIdx.x) >> 6;
    int lane = threadIdx.x & 63;
    if (n >= N_NODES) return;
    int start = rowptr[n], end = rowptr[n + 1];

    float2 xr2 = *(const float2*)&xr[(size_t)n * 128 + 2 * lane];
    float2 a2  = *(const float2*)&att[2 * lane];
    float2 bb  = *(const float2*)&bias[2 * lane];

    float m = -1e30f, den = 0.f, accx = 0.f, accy = 0.f;

    auto lane_t = [&](float2 c) {
        float v0 = c.x + xr2.x, v1 = c.y + xr2.y;
        v0 = (v0 > 0.f) ? v0 : NEG_SLOPE * v0;
        v1 = (v1 > 0.f) ? v1 : NEG_SLOPE * v1;
        return fmaf(v0, a2.x, v1 * a2.y);
    };
    auto update = [&](float sc, float2 c) {
        float mn = fmaxf(m, sc);
        float corr = __expf(m - mn);
        float p = __expf(sc - mn);
        m = mn;
        den = fmaf(den, corr, p);
        accx = fmaf(accx, corr, p * c.x);
        accy = fmaf(accy, corr, p * c.y);
    };

    int s0 = esrc[start];
    float2 r0 = *(const float2*)&xl[(size_t)s0 * 128 + 2 * lane];
    float2 r1 = r0;
    if (start + 1 < end) {
        int s1 = esrc[start + 1];
        r1 = *(const float2*)&xl[(size_t)s1 * 128 + 2 * lane];
    }

    int i = start;
    for (; i + 1 < end; i += 2) {
        float2 c0 = r0, c1 = r1;
        if (i + 2 < end) {
            int sa = esrc[i + 2];
            r0 = *(const float2*)&xl[(size_t)sa * 128 + 2 * lane];
        }
        if (i + 3 < end) {
            int sb = esrc[i + 3];
            r1 = *(const float2*)&xl[(size_t)sb * 128 + 2 * lane];
        }
        float t0 = lane_t(c0);
        float t1 = lane_t(c1);
        const int TOP = (H == 2) ? 16 : 32;
#pragma unroll
        for (int off = 1; off <= TOP; off <<= 1) {
            float u0 = __shfl_xor(t0, off, 64);
            float u1 = __shfl_xor(t1, off, 64);
            t0 += u0;
            t1 += u1;
        }
        update(t0, c0);
        update(t1, c1);
    }
    if (i < end) {
        float2 c0 = r0;
        float t0 = lane_t(c0);
        const int TOP = (H == 2) ? 16 : 32;
#pragma unroll
        for (int off = 1; off <= TOP; off <<= 1)
            t0 += __shfl_xor(t0, off, 64);
        update(t0, c0);
    }

    float inv = 1.f / (den + 1e-16f);
    float o0 = fmaf(accx, inv, bb.x);
    float o1 = fmaf(accy, inv, bb.y);
    o0 = (o0 > 0.f) ? o0 : (__expf(o0) - 1.f);   // ELU
    o1 = (o1 > 0.f) ? o1 : (__expf(o1) - 1.f);
    if (BF16OUT) {
        unsigned short h0 = f2bf(o0), h1 = f2bf(o1);
        unsigned short l0 = f2bf(o0 - bf2f(h0)), l1 = f2bf(o1 - bf2f(h1));
        ushort2 hi2; hi2.x = h0; hi2.y = h1;
        ushort2 lo2; lo2.x = l0; lo2.y = l1;
        *(ushort2*)&outb[(size_t)n * 256 + 2 * lane] = hi2;
        *(ushort2*)&outb[(size_t)n * 256 + 128 + 2 * lane] = lo2;
    } else {
        *(float2*)&out[(size_t)n * 128 + 2 * lane] = make_float2(o0, o1);
    }
}

// ---------------------------------------------------------------- launch
extern "C" void kernel_launch(void* const* d_in, const int* in_sizes, int n_in,
                              void* d_out, int out_size, void* d_ws, size_t ws_size,
                              hipStream_t stream) {
    const float* x    = (const float*)d_in[0];
    const int*   ei   = (const int*)d_in[1];
    const float* Wl1  = (const float*)d_in[2];
    const float* Wr1  = (const float*)d_in[3];
    const float* att1 = (const float*)d_in[4];
    const float* b1   = (const float*)d_in[5];
    const float* Wl2  = (const float*)d_in[6];
    const float* Wr2  = (const float*)d_in[7];
    const float* att2 = (const float*)d_in[8];
    const float* b2   = (const float*)d_in[9];
    const int* srcp = ei;
    const int* dstp = ei + N_EDGES;

    char* ws = (char*)d_ws;
    size_t off = 0;
    auto alloc = [&](size_t bytes) {
        void* p = ws + off;
        off = (off + bytes + 255) & ~(size_t)255;
        return p;
    };
    int*   rowptr = (int*)alloc((N_NODES + 1) * sizeof(int));
    int*   cursor = (int*)alloc((N_NODES + 1) * sizeof(int));
    int*   esrc   = (int*)alloc((size_t)TOT_E * sizeof(int));
    int*   bsum   = (int*)alloc(NBLK * sizeof(int));
    int*   boffs  = (int*)alloc(NBLK * sizeof(int));
    unsigned short* xp  = (unsigned short*)alloc((size_t)N_NODES * 256 * sizeof(short)); // hi|lo A'; reused as h1'
    unsigned short* Bp1 = (unsigned short*)alloc(65536 * sizeof(short));
    unsigned short* Bp2 = (unsigned short*)alloc(65536 * sizeof(short));
    float* xl     = (float*)alloc((size_t)N_NODES * 128 * sizeof(float));
    float* xr     = (float*)alloc((size_t)N_NODES * 128 * sizeof(float));

    // CSR build (graph is identical for both layers)
    hipMemsetAsync(rowptr, 0, (N_NODES + 1) * sizeof(int), stream);
    k_hist<<<(TOT_E + 255) / 256, 256, 0, stream>>>(dstp, rowptr);
    k_scan_a<<<NBLK, SCAN_B, 0, stream>>>(rowptr, bsum);
    k_scan_b<<<1, 64, 0, stream>>>(bsum, boffs);
    k_scan_c<<<(N_NODES + 255) / 256, 256, 0, stream>>>(rowptr, boffs, cursor);
    k_scatter<<<(TOT_E + 255) / 256, 256, 0, stream>>>(srcp, dstp, cursor, esrc);

    // precision prep
    k_split<<<(N_NODES * 32 + 255) / 256, 256, 0, stream>>>(x, xp);
    k_pack<<<256, 256, 0, stream>>>(Wl1, Wr1, Bp1);
    k_pack<<<256, 256, 0, stream>>>(Wl2, Wr2, Bp2);

    int mfma_grid = (N_NODES + 63) / 64;

    // layer 1: heads=2, C=64, concat
    k_mfma_lin<<<mfma_grid, 256, 0, stream>>>(xp, Bp1, xl, xr, N_NODES);
    k_gat<2, true><<<(N_NODES + 3) / 4, 256, 0, stream>>>(rowptr, esrc, xl, xr, att1, b1,
                                                          nullptr, xp);
    // layer 2: heads=1, C=128, mean over 1 head = identity
    k_mfma_lin<<<mfma_grid, 256, 0, stream>>>(xp, Bp2, xl, xr, N_NODES);
    k_gat<1, false><<<(N_NODES + 3) / 4, 256, 0, stream>>>(rowptr, esrc, xl, xr, att2, b2,
                                                           (float*)d_out, nullptr);
}

// Round 6
// 245.728 us; speedup vs baseline: 4.0137x; 1.4024x over previous
//
#include <hip/hip_runtime.h>
#include <hip/hip_bf16.h>

#define N_NODES 50000
#define N_EDGES 800000
#define TOT_E   (N_EDGES + N_NODES)   // edges + self loops = 850000
#define NEG_SLOPE 0.2f
#define SCAN_B 1024
#define NBLK ((N_NODES + SCAN_B - 1) / SCAN_B)   // 49

typedef __attribute__((ext_vector_type(8))) short bf16x8;
typedef __attribute__((ext_vector_type(4))) float f32x4;

static __device__ __forceinline__ unsigned short f2bf(float f) {
    unsigned int u = __float_as_uint(f);
    unsigned int r = (u + 0x7FFFu + ((u >> 16) & 1u)) >> 16;   // RNE
    return (unsigned short)r;
}
static __device__ __forceinline__ float bf2f(unsigned short h) {
    return __uint_as_float(((unsigned int)h) << 16);
}
static __device__ __forceinline__ unsigned short f2h(float f) {
    _Float16 h = (_Float16)f;                                   // v_cvt_f16_f32 (RNE)
    return __builtin_bit_cast(unsigned short, h);
}
static __device__ __forceinline__ float h2f(unsigned short u) {
    return (float)__builtin_bit_cast(_Float16, u);
}

// ---------------------------------------------------------------- CSR build
__global__ void k_hist(const int* __restrict__ dstp, int* __restrict__ rowptr) {
    int e = blockIdx.x * blockDim.x + threadIdx.x;
    if (e < TOT_E) {
        int d = (e < N_EDGES) ? dstp[e] : (e - N_EDGES);
        atomicAdd(&rowptr[d + 1], 1);
    }
}

__global__ __launch_bounds__(SCAN_B) void k_scan_a(int* __restrict__ rowptr,
                                                   int* __restrict__ bsum) {
    __shared__ int sh[SCAN_B];
    int t = threadIdx.x;
    int i = blockIdx.x * SCAN_B + t;
    int v = (i < N_NODES) ? rowptr[i + 1] : 0;
    sh[t] = v;
    __syncthreads();
    for (int off = 1; off < SCAN_B; off <<= 1) {
        int u = (t >= off) ? sh[t - off] : 0;
        __syncthreads();
        sh[t] += u;
        __syncthreads();
    }
    if (i < N_NODES) rowptr[i + 1] = sh[t];
    if (t == SCAN_B - 1) bsum[blockIdx.x] = sh[t];
}

__global__ void k_scan_b(const int* __restrict__ bsum, int* __restrict__ boffs) {
    int t = threadIdx.x;   // 64 threads
    int own = (t < NBLK) ? bsum[t] : 0;
    int v = own;
#pragma unroll
    for (int off = 1; off < 64; off <<= 1) {
        int u = __shfl_up(v, off, 64);
        if (t >= off) v += u;
    }
    if (t < NBLK) boffs[t] = v - own;
}

__global__ void k_scan_c(int* __restrict__ rowptr, const int* __restrict__ boffs,
                         int* __restrict__ cursor) {
    int i = blockIdx.x * 256 + threadIdx.x;
    if (i < N_NODES) {
        int val = rowptr[i + 1] + boffs[i >> 10];
        rowptr[i + 1] = val;
        cursor[i + 1] = val;
    }
    if (i == 0) { rowptr[0] = 0; cursor[0] = 0; }
}

__global__ void k_scatter(const int* __restrict__ srcp, const int* __restrict__ dstp,
                          int* __restrict__ cursor, int* __restrict__ esrc) {
    int e = blockIdx.x * blockDim.x + threadIdx.x;
    if (e < TOT_E) {
        int d = (e < N_EDGES) ? dstp[e] : (e - N_EDGES);
        int s = (e < N_EDGES) ? srcp[e] : (e - N_EDGES);
        int pos = atomicAdd(&cursor[d], 1);
        esrc[pos] = s;
    }
}

// ------------------------------------------------- f32 -> (hi|lo) bf16 split
__global__ void k_split(const float* __restrict__ X, unsigned short* __restrict__ Ap) {
    int t = blockIdx.x * 256 + threadIdx.x;   // one float4 per thread
    if (t >= N_NODES * 32) return;
    int row = t >> 5, c4 = (t & 31) * 4;
    float4 v = *(const float4*)&X[(size_t)row * 128 + c4];
    float vv[4] = {v.x, v.y, v.z, v.w};
    ushort4 hh, ll;
    unsigned short* hp = &hh.x;
    unsigned short* lp = &ll.x;
#pragma unroll
    for (int i = 0; i < 4; ++i) {
        unsigned short h = f2bf(vv[i]);
        hp[i] = h;
        lp[i] = f2bf(vv[i] - bf2f(h));
    }
    *(ushort4*)&Ap[(size_t)row * 256 + c4] = hh;
    *(ushort4*)&Ap[(size_t)row * 256 + 128 + c4] = ll;
}

// ------------------------------------------------- weight pack -> MFMA frag order
__global__ void k_pack(const float* __restrict__ Wa, const float* __restrict__ Wb,
                       unsigned short* __restrict__ Bp) {
    int idx = blockIdx.x * 256 + threadIdx.x;   // 65536 total
    int j = idx & 7, lane = (idx >> 3) & 63, t = idx >> 9;
    int ks = t >> 4, ctg = t & 15;
    int k = (ks * 32 + (lane >> 4) * 8 + j) & 127;
    int n = ctg * 16 + (lane & 15);
    float v = (n < 128) ? Wa[k * 128 + n] : Wb[k * 128 + (n - 128)];
    Bp[idx] = f2bf(v);
}

// ------------------------------------------------- MFMA dual linear -> fp16 out
__global__ __launch_bounds__(256) void k_mfma_lin(const unsigned short* __restrict__ Ap,
                                                  const unsigned short* __restrict__ Bp,
                                                  unsigned short* __restrict__ outA,
                                                  unsigned short* __restrict__ outB, int M) {
    __shared__ unsigned short lds_a[64][264];   // +8 pad
    int tid = threadIdx.x;
    int n0 = blockIdx.x * 64;
#pragma unroll
    for (int r = 0; r < 8; ++r) {
        int c = r * 256 + tid;
        int row = c >> 5;
        int col = (c & 31) * 8;
        int gr = n0 + row;
        if (gr >= M) gr = M - 1;
        float4 v = *(const float4*)&Ap[(size_t)gr * 256 + col];
        *(float4*)&lds_a[row][col] = v;
    }
    __syncthreads();

    int w = tid >> 6, lane = tid & 63;
    int lrow = lane & 15, lhi = lane >> 4;
    f32x4 acc[4][4] = {};
    const bf16x8* Bf = (const bf16x8*)Bp;
#pragma unroll
    for (int ks = 0; ks < 8; ++ks) {
        bf16x8 bfr[4], afr[4];
#pragma unroll
        for (int ct = 0; ct < 4; ++ct)
            bfr[ct] = Bf[(ks * 16 + (w * 4 + ct)) * 64 + lane];
#pragma unroll
        for (int mt = 0; mt < 4; ++mt)
            afr[mt] = *(const bf16x8*)&lds_a[mt * 16 + lrow][ks * 32 + lhi * 8];
#pragma unroll
        for (int mt = 0; mt < 4; ++mt)
#pragma unroll
            for (int ct = 0; ct < 4; ++ct)
                acc[mt][ct] = __builtin_amdgcn_mfma_f32_16x16x32_bf16(
                    afr[mt], bfr[ct], acc[mt][ct], 0, 0, 0);
    }
#pragma unroll
    for (int mt = 0; mt < 4; ++mt) {
        int row0 = n0 + mt * 16 + lhi * 4;
#pragma unroll
        for (int ct = 0; ct < 4; ++ct) {
            int col = w * 64 + ct * 16 + lrow;
            unsigned short* dst = (col < 128) ? outA : outB;   // wave-uniform
            int cc = col & 127;
#pragma unroll
            for (int reg = 0; reg < 4; ++reg) {
                int rg = row0 + reg;
                if (rg < M) dst[(size_t)rg * 128 + cc] = f2h(acc[mt][ct][reg]);
            }
        }
    }
}

// ------------------------------------------------- fused score+softmax+aggregate
// One wave per node; 16 lanes per edge slot, 4 edge slots per wave.
// lane: grp = lane>>4 (edge slot), sub = lane&15; lane owns elems sub*8..+7
// (one uint4 = 8 fp16 per gather). H=2: head = sub>>3, score reduce = 3
// shfl_xor over 8 lanes; H=1: 4 shfl_xor over 16. Invalid slots: sc=-1e38
// -> p=0. Per-lane online softmax; 2 merge rounds (xor 16,32) per node.
template <int H, bool BF16OUT>
__global__ __launch_bounds__(256) void k_gat(const int* __restrict__ rowptr,
                                             const int* __restrict__ esrc,
                                             const unsigned short* __restrict__ xlh,
                                             const unsigned short* __restrict__ xrh,
                                             const float* __restrict__ att,
                                             const float* __restrict__ bias,
                                             float* __restrict__ out,
                                             unsigned short* __restrict__ outb) {
    int n = (blockIdx.x * 256 + threadIdx.x) >> 6;
    int lane = threadIdx.x & 63;
    if (n >= N_NODES) return;
    int start = rowptr[n], end = rowptr[n + 1];
    int grp = lane >> 4, sub = lane & 15;
    int c0 = sub * 8;

    float xr8[8], a8[8];
    {
        uint4 u = *(const uint4*)&xrh[(size_t)n * 128 + c0];
        unsigned int uu[4] = {u.x, u.y, u.z, u.w};
#pragma unroll
        for (int q = 0; q < 4; ++q) {
            xr8[2 * q]     = h2f((unsigned short)uu[q]);
            xr8[2 * q + 1] = h2f((unsigned short)(uu[q] >> 16));
        }
        float4 av0 = *(const float4*)&att[c0];
        float4 av1 = *(const float4*)&att[c0 + 4];
        a8[0] = av0.x; a8[1] = av0.y; a8[2] = av0.z; a8[3] = av0.w;
        a8[4] = av1.x; a8[5] = av1.y; a8[6] = av1.z; a8[7] = av1.w;
    }

    float m = -1e30f, den = 0.f;
    float acc[8] = {0.f, 0.f, 0.f, 0.f, 0.f, 0.f, 0.f, 0.f};

    // prefetch first batch
    int e0 = start + grp;
    int sp = esrc[(e0 < end) ? e0 : (end - 1)];
    uint4 u = *(const uint4*)&xlh[(size_t)sp * 128 + c0];

    for (int i = start; i < end; i += 4) {
        bool valid = (i + grp) < end;
        uint4 uc = u;
        int enext = i + 4 + grp;
        if (enext < end) {                       // prefetch next batch
            int s2 = esrc[enext];
            u = *(const uint4*)&xlh[(size_t)s2 * 128 + c0];
        }
        unsigned int uu[4] = {uc.x, uc.y, uc.z, uc.w};
        float c[8];
#pragma unroll
        for (int q = 0; q < 4; ++q) {
            c[2 * q]     = h2f((unsigned short)uu[q]);
            c[2 * q + 1] = h2f((unsigned short)(uu[q] >> 16));
        }
        float t = 0.f;
#pragma unroll
        for (int j = 0; j < 8; ++j) {
            float v = c[j] + xr8[j];
            v = fmaxf(v, NEG_SLOPE * v);         // leaky-relu, slope<1
            t = fmaf(v, a8[j], t);
        }
        const int STEPS = (H == 2) ? 3 : 4;      // 8-lane vs 16-lane reduce
#pragma unroll
        for (int k = 0; k < STEPS; ++k)
            t += __shfl_xor(t, 1 << k, 64);
        float sc = valid ? t : -1e38f;

        float mn = fmaxf(m, sc);
        float corr = __expf(m - mn);
        float p = __expf(sc - mn);
        m = mn;
        den = fmaf(den, corr, p);
#pragma unroll
        for (int j = 0; j < 8; ++j)
            acc[j] = fmaf(acc[j], corr, p * c[j]);
    }

    // merge the 4 edge-slot groups (xor 16, then 32)
#pragma unroll
    for (int off = 16; off <= 32; off <<= 1) {
        float mo = __shfl_xor(m, off, 64);
        float deno = __shfl_xor(den, off, 64);
        float ao[8];
#pragma unroll
        for (int j = 0; j < 8; ++j) ao[j] = __shfl_xor(acc[j], off, 64);
        float mn = fmaxf(m, mo);
        float c1 = __expf(m - mn);
        float c2 = __expf(mo - mn);
        m = mn;
        den = den * c1 + deno * c2;
#pragma unroll
        for (int j = 0; j < 8; ++j)
            acc[j] = fmaf(acc[j], c1, ao[j] * c2);
    }

    if (grp == 0) {
        float inv = 1.f / (den + 1e-16f);
        float o[8];
        float4 bv0 = *(const float4*)&bias[c0];
        float4 bv1 = *(const float4*)&bias[c0 + 4];
        float bb[8] = {bv0.x, bv0.y, bv0.z, bv0.w, bv1.x, bv1.y, bv1.z, bv1.w};
#pragma unroll
        for (int j = 0; j < 8; ++j) {
            float v = fmaf(acc[j], inv, bb[j]);
            o[j] = (v > 0.f) ? v : (__expf(v) - 1.f);   // ELU
        }
        if (BF16OUT) {
            unsigned short hi[8], lo[8];
#pragma unroll
            for (int j = 0; j < 8; ++j) {
                hi[j] = f2bf(o[j]);
                lo[j] = f2bf(o[j] - bf2f(hi[j]));
            }
            *(uint4*)&outb[(size_t)n * 256 + c0] = *(const uint4*)hi;
            *(uint4*)&outb[(size_t)n * 256 + 128 + c0] = *(const uint4*)lo;
        } else {
            *(float4*)&out[(size_t)n * 128 + c0] = make_float4(o[0], o[1], o[2], o[3]);
            *(float4*)&out[(size_t)n * 128 + c0 + 4] = make_float4(o[4], o[5], o[6], o[7]);
        }
    }
}

// ---------------------------------------------------------------- launch
extern "C" void kernel_launch(void* const* d_in, const int* in_sizes, int n_in,
                              void* d_out, int out_size, void* d_ws, size_t ws_size,
                              hipStream_t stream) {
    const float* x    = (const float*)d_in[0];
    const int*   ei   = (const int*)d_in[1];
    const float* Wl1  = (const float*)d_in[2];
    const float* Wr1  = (const float*)d_in[3];
    const float* att1 = (const float*)d_in[4];
    const float* b1   = (const float*)d_in[5];
    const float* Wl2  = (const float*)d_in[6];
    const float* Wr2  = (const float*)d_in[7];
    const float* att2 = (const float*)d_in[8];
    const float* b2   = (const float*)d_in[9];
    const int* srcp = ei;
    const int* dstp = ei + N_EDGES;

    char* ws = (char*)d_ws;
    size_t off = 0;
    auto alloc = [&](size_t bytes) {
        void* p = ws + off;
        off = (off + bytes + 255) & ~(size_t)255;
        return p;
    };
    int*   rowptr = (int*)alloc((N_NODES + 1) * sizeof(int));
    int*   cursor = (int*)alloc((N_NODES + 1) * sizeof(int));
    int*   esrc   = (int*)alloc((size_t)TOT_E * sizeof(int));
    int*   bsum   = (int*)alloc(NBLK * sizeof(int));
    int*   boffs  = (int*)alloc(NBLK * sizeof(int));
    unsigned short* xp  = (unsigned short*)alloc((size_t)N_NODES * 256 * sizeof(short)); // hi|lo A'; reused as h1'
    unsigned short* Bp1 = (unsigned short*)alloc(65536 * sizeof(short));
    unsigned short* Bp2 = (unsigned short*)alloc(65536 * sizeof(short));
    unsigned short* xl  = (unsigned short*)alloc((size_t)N_NODES * 128 * sizeof(short)); // fp16
    unsigned short* xr  = (unsigned short*)alloc((size_t)N_NODES * 128 * sizeof(short)); // fp16

    // CSR build (graph is identical for both layers)
    hipMemsetAsync(rowptr, 0, (N_NODES + 1) * sizeof(int), stream);
    k_hist<<<(TOT_E + 255) / 256, 256, 0, stream>>>(dstp, rowptr);
    k_scan_a<<<NBLK, SCAN_B, 0, stream>>>(rowptr, bsum);
    k_scan_b<<<1, 64, 0, stream>>>(bsum, boffs);
    k_scan_c<<<(N_NODES + 255) / 256, 256, 0, stream>>>(rowptr, boffs, cursor);
    k_scatter<<<(TOT_E + 255) / 256, 256, 0, stream>>>(srcp, dstp, cursor, esrc);

    // precision prep
    k_split<<<(N_NODES * 32 + 255) / 256, 256, 0, stream>>>(x, xp);
    k_pack<<<256, 256, 0, stream>>>(Wl1, Wr1, Bp1);
    k_pack<<<256, 256, 0, stream>>>(Wl2, Wr2, Bp2);

    int mfma_grid = (N_NODES + 63) / 64;

    // layer 1: heads=2, C=64, concat
    k_mfma_lin<<<mfma_grid, 256, 0, stream>>>(xp, Bp1, xl, xr, N_NODES);
    k_gat<2, true><<<(N_NODES + 3) / 4, 256, 0, stream>>>(rowptr, esrc, xl, xr, att1, b1,
                                                          nullptr, xp);
    // layer 2: heads=1, C=128, mean over 1 head = identity
    k_mfma_lin<<<mfma_grid, 256, 0, stream>>>(xp, Bp2, xl, xr, N_NODES);
    k_gat<1, false><<<(N_NODES + 3) / 4, 256, 0, stream>>>(rowptr, esrc, xl, xr, att2, b2,
                                                           (float*)d_out, nullptr);
}

// Round 7
// 170.900 us; speedup vs baseline: 5.7710x; 1.4378x over previous
//
#include <hip/hip_runtime.h>
#include <hip/hip_bf16.h>

#define N_NODES 50000
#define N_EDGES 800000
#define TOT_E   (N_EDGES + N_NODES)   // edges + self loops = 850000
#define NEG_SLOPE 0.2f
#define NBKT 98          // buckets of 512 nodes: 98*512 = 50176 >= 50000
#define CHUNK 4096       // edges per block in pass A
#define NCHUNK ((TOT_E + CHUNK - 1) / CHUNK)   // 208
#define BKT_CAP 12288    // max edges per bucket (mean 8704, sd ~93)

typedef __attribute__((ext_vector_type(8))) short bf16x8;
typedef __attribute__((ext_vector_type(4))) float f32x4;

static __device__ __forceinline__ unsigned short f2bf(float f) {
    unsigned int u = __float_as_uint(f);
    unsigned int r = (u + 0x7FFFu + ((u >> 16) & 1u)) >> 16;   // RNE
    return (unsigned short)r;
}
static __device__ __forceinline__ float bf2f(unsigned short h) {
    return __uint_as_float(((unsigned int)h) << 16);
}
static __device__ __forceinline__ unsigned short f2h(float f) {
    _Float16 h = (_Float16)f;                                   // v_cvt_f16_f32 (RNE)
    return __builtin_bit_cast(unsigned short, h);
}
static __device__ __forceinline__ float h2f(unsigned short u) {
    return (float)__builtin_bit_cast(_Float16, u);
}

// ---------------------------------------------------------------- CSR build
// Pass A1: per-block LDS bucket histogram -> 98 global atomics per block
__global__ __launch_bounds__(1024) void kA1(const int* __restrict__ dstp,
                                            int* __restrict__ bcount) {
    __shared__ int h[NBKT];
    int t = threadIdx.x;
    if (t < NBKT) h[t] = 0;
    __syncthreads();
    int base = blockIdx.x * CHUNK;
    int nloc = min(CHUNK, TOT_E - base);
    for (int i = t; i < nloc; i += 1024) {
        int e = base + i;
        int d = (e < N_EDGES) ? dstp[e] : (e - N_EDGES);
        atomicAdd(&h[d >> 9], 1);
    }
    __syncthreads();
    if (t < NBKT && h[t]) atomicAdd(&bcount[t], h[t]);
}

// scan the 98 bucket counts -> bbase (exclusive, 99 entries), init bcursor
__global__ void kScan98(const int* __restrict__ bcount, int* __restrict__ bbase,
                        int* __restrict__ bcursor) {
    __shared__ int s[128];
    int t = threadIdx.x;   // 128 threads
    int own = (t < NBKT) ? bcount[t] : 0;
    s[t] = own;
    __syncthreads();
    for (int off = 1; off < 128; off <<= 1) {
        int v = (t >= off) ? s[t - off] : 0;
        __syncthreads();
        s[t] += v;
        __syncthreads();
    }
    if (t < NBKT) {
        int base = s[t] - own;
        bbase[t] = base;
        bcursor[t] = base;
    }
    if (t == NBKT - 1) bbase[NBKT] = s[t];
}

// Pass A2: LDS counting-sort of the chunk by bucket, coalesced run dump.
// packed u32: src[0:16) | local_dst[16:25) | bucket[25:32)
__global__ __launch_bounds__(1024) void kA2(const int* __restrict__ srcp,
                                            const int* __restrict__ dstp,
                                            int* __restrict__ bcursor,
                                            unsigned* __restrict__ ebuf) {
    __shared__ int h[NBKT];
    __shared__ int lbase[NBKT];
    __shared__ int lcur[NBKT];
    __shared__ unsigned stage[CHUNK];
    int t = threadIdx.x;
    if (t < NBKT) h[t] = 0;
    __syncthreads();
    int base = blockIdx.x * CHUNK;
    int nloc = min(CHUNK, TOT_E - base);
    for (int i = t; i < nloc; i += 1024) {
        int e = base + i;
        int d = (e < N_EDGES) ? dstp[e] : (e - N_EDGES);
        atomicAdd(&h[d >> 9], 1);
    }
    __syncthreads();
    if (t < NBKT) lbase[t] = h[t] ? atomicAdd(&bcursor[t], h[t]) : 0;
    if (t == 0) {
        int run = 0;
        for (int b = 0; b < NBKT; ++b) { lcur[b] = run; run += h[b]; }
    }
    __syncthreads();
    for (int i = t; i < nloc; i += 1024) {
        int e = base + i;
        int d = (e < N_EDGES) ? dstp[e] : (e - N_EDGES);
        int s = (e < N_EDGES) ? srcp[e] : (e - N_EDGES);
        int b = d >> 9;
        int p = atomicAdd(&lcur[b], 1);
        stage[p] = (unsigned)s | ((unsigned)(d & 511) << 16) | ((unsigned)b << 25);
    }
    __syncthreads();
    // stage is bucket-sorted: linear read -> per-bucket contiguous global runs
    for (int i = t; i < nloc; i += 1024) {
        unsigned v = stage[i];
        int b = v >> 25;
        int p = lbase[b] + i - (lcur[b] - h[b]);
        ebuf[p] = v & 0x1FFFFFFu;
    }
}

// Pass B: one block per bucket -> exact CSR (rowptr + esrc), all coalesced
__global__ __launch_bounds__(1024) void kB(const unsigned* __restrict__ ebuf,
                                           const int* __restrict__ bbase,
                                           int* __restrict__ rowptr,
                                           int* __restrict__ esrc) {
    __shared__ int h[512];
    __shared__ int sc[512];
    __shared__ int st2[BKT_CAP];
    int b = blockIdx.x;
    int t = threadIdx.x;
    int gb = bbase[b];
    int cnt = bbase[b + 1] - gb;
    if (t < 512) h[t] = 0;
    __syncthreads();
    for (int i = t; i < cnt; i += 1024)
        atomicAdd(&h[(ebuf[gb + i] >> 16) & 511], 1);
    __syncthreads();
    if (t < 512) sc[t] = h[t];
    __syncthreads();
    for (int off = 1; off < 512; off <<= 1) {
        int v = (t < 512 && t >= off) ? sc[t - off] : 0;
        __syncthreads();
        if (t < 512) sc[t] += v;
        __syncthreads();
    }
    if (t < 512) h[t] = sc[t] - h[t];   // h := exclusive scan (scatter cursor)
    __syncthreads();
    int node0 = b << 9;
    if (t < 512) {
        int gn = node0 + t;
        if (gn < N_NODES) rowptr[gn] = gb + h[t];
    }
    if (b == NBKT - 1 && t == 0) rowptr[N_NODES] = TOT_E;
    for (int i = t; i < cnt; i += 1024) {
        unsigned v = ebuf[gb + i];
        int p = atomicAdd(&h[(v >> 16) & 511], 1);
        st2[p] = (int)(v & 0xFFFFu);
    }
    __syncthreads();
    for (int i = t; i < cnt; i += 1024) esrc[gb + i] = st2[i];
}

// ------------------------------------------------- weight pack -> MFMA frag order
__global__ void k_pack(const float* __restrict__ Wa, const float* __restrict__ Wb,
                       unsigned short* __restrict__ Bp) {
    int idx = blockIdx.x * 256 + threadIdx.x;   // 65536 total
    int j = idx & 7, lane = (idx >> 3) & 63, t = idx >> 9;
    int ks = t >> 4, ctg = t & 15;
    int k = (ks * 32 + (lane >> 4) * 8 + j) & 127;
    int n = ctg * 16 + (lane & 15);
    float v = (n < 128) ? Wa[k * 128 + n] : Wb[k * 128 + (n - 128)];
    Bp[idx] = f2bf(v);
}

// ------------------------------------------------- MFMA dual linear -> fp16 out
// F32IN: stage f32 input, converting to hi/lo bf16 on the fly (k_split folded in).
template <bool F32IN>
__global__ __launch_bounds__(256) void k_mfma_lin(const void* __restrict__ Ain,
                                                  const unsigned short* __restrict__ Bp,
                                                  unsigned short* __restrict__ outA,
                                                  unsigned short* __restrict__ outB, int M) {
    __shared__ unsigned short lds_a[64][264];   // +8 pad
    int tid = threadIdx.x;
    int n0 = blockIdx.x * 64;
    if (F32IN) {
        const float* X = (const float*)Ain;
#pragma unroll
        for (int r = 0; r < 8; ++r) {
            int c = r * 256 + tid;
            int row = c >> 5;
            int col4 = (c & 31) * 4;
            int gr = n0 + row;
            if (gr >= M) gr = M - 1;
            float4 v = *(const float4*)&X[(size_t)gr * 128 + col4];
            float vv[4] = {v.x, v.y, v.z, v.w};
            ushort4 hh, ll;
            unsigned short* hp = &hh.x;
            unsigned short* lp = &ll.x;
#pragma unroll
            for (int q = 0; q < 4; ++q) {
                unsigned short hv = f2bf(vv[q]);
                hp[q] = hv;
                lp[q] = f2bf(vv[q] - bf2f(hv));
            }
            *(ushort4*)&lds_a[row][col4] = hh;
            *(ushort4*)&lds_a[row][128 + col4] = ll;
        }
    } else {
        const unsigned short* Ap = (const unsigned short*)Ain;
#pragma unroll
        for (int r = 0; r < 8; ++r) {
            int c = r * 256 + tid;
            int row = c >> 5;
            int col = (c & 31) * 8;
            int gr = n0 + row;
            if (gr >= M) gr = M - 1;
            float4 v = *(const float4*)&Ap[(size_t)gr * 256 + col];
            *(float4*)&lds_a[row][col] = v;
        }
    }
    __syncthreads();

    int w = tid >> 6, lane = tid & 63;
    int lrow = lane & 15, lhi = lane >> 4;
    f32x4 acc[4][4] = {};
    const bf16x8* Bf = (const bf16x8*)Bp;
#pragma unroll
    for (int ks = 0; ks < 8; ++ks) {
        bf16x8 bfr[4], afr[4];
#pragma unroll
        for (int ct = 0; ct < 4; ++ct)
            bfr[ct] = Bf[(ks * 16 + (w * 4 + ct)) * 64 + lane];
#pragma unroll
        for (int mt = 0; mt < 4; ++mt)
            afr[mt] = *(const bf16x8*)&lds_a[mt * 16 + lrow][ks * 32 + lhi * 8];
#pragma unroll
        for (int mt = 0; mt < 4; ++mt)
#pragma unroll
            for (int ct = 0; ct < 4; ++ct)
                acc[mt][ct] = __builtin_amdgcn_mfma_f32_16x16x32_bf16(
                    afr[mt], bfr[ct], acc[mt][ct], 0, 0, 0);
    }
#pragma unroll
    for (int mt = 0; mt < 4; ++mt) {
        int row0 = n0 + mt * 16 + lhi * 4;
#pragma unroll
        for (int ct = 0; ct < 4; ++ct) {
            int col = w * 64 + ct * 16 + lrow;
            unsigned short* dst = (col < 128) ? outA : outB;   // wave-uniform
            int cc = col & 127;
#pragma unroll
            for (int reg = 0; reg < 4; ++reg) {
                int rg = row0 + reg;
                if (rg < M) dst[(size_t)rg * 128 + cc] = f2h(acc[mt][ct][reg]);
            }
        }
    }
}

// ------------------------------------------------- fused score+softmax+aggregate
// One wave per node; 16 lanes per edge slot, 4 edge slots per wave.
// lane: grp = lane>>4 (edge slot), sub = lane&15; lane owns elems sub*8..+7.
// H=2: head = sub>>3, score reduce = 3 shfl_xor over 8 lanes; H=1: 4 over 16.
// Invalid slots: sc=-1e38 -> p=0. Per-lane online softmax; 2 merge rounds.
template <int H, bool BF16OUT>
__global__ __launch_bounds__(256) void k_gat(const int* __restrict__ rowptr,
                                             const int* __restrict__ esrc,
                                             const unsigned short* __restrict__ xlh,
                                             const unsigned short* __restrict__ xrh,
                                             const float* __restrict__ att,
                                             const float* __restrict__ bias,
                                             float* __restrict__ out,
                                             unsigned short* __restrict__ outb) {
    int n = (blockIdx.x * 256 + threadIdx.x) >> 6;
    int lane = threadIdx.x & 63;
    if (n >= N_NODES) return;
    int start = rowptr[n], end = rowptr[n + 1];
    int grp = lane >> 4, sub = lane & 15;
    int c0 = sub * 8;

    float xr8[8], a8[8];
    {
        uint4 u = *(const uint4*)&xrh[(size_t)n * 128 + c0];
        unsigned int uu[4] = {u.x, u.y, u.z, u.w};
#pragma unroll
        for (int q = 0; q < 4; ++q) {
            xr8[2 * q]     = h2f((unsigned short)uu[q]);
            xr8[2 * q + 1] = h2f((unsigned short)(uu[q] >> 16));
        }
        float4 av0 = *(const float4*)&att[c0];
        float4 av1 = *(const float4*)&att[c0 + 4];
        a8[0] = av0.x; a8[1] = av0.y; a8[2] = av0.z; a8[3] = av0.w;
        a8[4] = av1.x; a8[5] = av1.y; a8[6] = av1.z; a8[7] = av1.w;
    }

    float m = -1e30f, den = 0.f;
    float acc[8] = {0.f, 0.f, 0.f, 0.f, 0.f, 0.f, 0.f, 0.f};

    int e0 = start + grp;
    int sp = esrc[(e0 < end) ? e0 : (end - 1)];
    uint4 u = *(const uint4*)&xlh[(size_t)sp * 128 + c0];

    for (int i = start; i < end; i += 4) {
        bool valid = (i + grp) < end;
        uint4 uc = u;
        int enext = i + 4 + grp;
        if (enext < end) {
            int s2 = esrc[enext];
            u = *(const uint4*)&xlh[(size_t)s2 * 128 + c0];
        }
        unsigned int uu[4] = {uc.x, uc.y, uc.z, uc.w};
        float c[8];
#pragma unroll
        for (int q = 0; q < 4; ++q) {
            c[2 * q]     = h2f((unsigned short)uu[q]);
            c[2 * q + 1] = h2f((unsigned short)(uu[q] >> 16));
        }
        float t = 0.f;
#pragma unroll
        for (int j = 0; j < 8; ++j) {
            float v = c[j] + xr8[j];
            v = fmaxf(v, NEG_SLOPE * v);
            t = fmaf(v, a8[j], t);
        }
        const int STEPS = (H == 2) ? 3 : 4;
#pragma unroll
        for (int k = 0; k < STEPS; ++k)
            t += __shfl_xor(t, 1 << k, 64);
        float sc = valid ? t : -1e38f;

        float mn = fmaxf(m, sc);
        float corr = __expf(m - mn);
        float p = __expf(sc - mn);
        m = mn;
        den = fmaf(den, corr, p);
#pragma unroll
        for (int j = 0; j < 8; ++j)
            acc[j] = fmaf(acc[j], corr, p * c[j]);
    }

#pragma unroll
    for (int off = 16; off <= 32; off <<= 1) {
        float mo = __shfl_xor(m, off, 64);
        float deno = __shfl_xor(den, off, 64);
        float ao[8];
#pragma unroll
        for (int j = 0; j < 8; ++j) ao[j] = __shfl_xor(acc[j], off, 64);
        float mn = fmaxf(m, mo);
        float c1 = __expf(m - mn);
        float c2 = __expf(mo - mn);
        m = mn;
        den = den * c1 + deno * c2;
#pragma unroll
        for (int j = 0; j < 8; ++j)
            acc[j] = fmaf(acc[j], c1, ao[j] * c2);
    }

    if (grp == 0) {
        float inv = 1.f / (den + 1e-16f);
        float o[8];
        float4 bv0 = *(const float4*)&bias[c0];
        float4 bv1 = *(const float4*)&bias[c0 + 4];
        float bb[8] = {bv0.x, bv0.y, bv0.z, bv0.w, bv1.x, bv1.y, bv1.z, bv1.w};
#pragma unroll
        for (int j = 0; j < 8; ++j) {
            float v = fmaf(acc[j], inv, bb[j]);
            o[j] = (v > 0.f) ? v : (__expf(v) - 1.f);   // ELU
        }
        if (BF16OUT) {
            unsigned short hi[8], lo[8];
#pragma unroll
            for (int j = 0; j < 8; ++j) {
                hi[j] = f2bf(o[j]);
                lo[j] = f2bf(o[j] - bf2f(hi[j]));
            }
            *(uint4*)&outb[(size_t)n * 256 + c0] = *(const uint4*)hi;
            *(uint4*)&outb[(size_t)n * 256 + 128 + c0] = *(const uint4*)lo;
        } else {
            *(float4*)&out[(size_t)n * 128 + c0] = make_float4(o[0], o[1], o[2], o[3]);
            *(float4*)&out[(size_t)n * 128 + c0 + 4] = make_float4(o[4], o[5], o[6], o[7]);
        }
    }
}

// ---------------------------------------------------------------- launch
extern "C" void kernel_launch(void* const* d_in, const int* in_sizes, int n_in,
                              void* d_out, int out_size, void* d_ws, size_t ws_size,
                              hipStream_t stream) {
    const float* x    = (const float*)d_in[0];
    const int*   ei   = (const int*)d_in[1];
    const float* Wl1  = (const float*)d_in[2];
    const float* Wr1  = (const float*)d_in[3];
    const float* att1 = (const float*)d_in[4];
    const float* b1   = (const float*)d_in[5];
    const float* Wl2  = (const float*)d_in[6];
    const float* Wr2  = (const float*)d_in[7];
    const float* att2 = (const float*)d_in[8];
    const float* b2   = (const float*)d_in[9];
    const int* srcp = ei;
    const int* dstp = ei + N_EDGES;

    char* ws = (char*)d_ws;
    size_t off = 0;
    auto alloc = [&](size_t bytes) {
        void* p = ws + off;
        off = (off + bytes + 255) & ~(size_t)255;
        return p;
    };
    int*      bcount  = (int*)alloc(NBKT * sizeof(int));
    int*      bbase   = (int*)alloc((NBKT + 1) * sizeof(int));
    int*      bcursor = (int*)alloc(NBKT * sizeof(int));
    unsigned* ebuf    = (unsigned*)alloc((size_t)TOT_E * sizeof(unsigned));
    int*      rowptr  = (int*)alloc((N_NODES + 1) * sizeof(int));
    int*      esrc    = (int*)alloc((size_t)TOT_E * sizeof(int));
    unsigned short* xp  = (unsigned short*)alloc((size_t)N_NODES * 256 * sizeof(short));
    unsigned short* Bp1 = (unsigned short*)alloc(65536 * sizeof(short));
    unsigned short* Bp2 = (unsigned short*)alloc(65536 * sizeof(short));
    unsigned short* xl  = (unsigned short*)alloc((size_t)N_NODES * 128 * sizeof(short));
    unsigned short* xr  = (unsigned short*)alloc((size_t)N_NODES * 128 * sizeof(short));

    // CSR build: bucketed counting sort, coalesced writes
    hipMemsetAsync(bcount, 0, NBKT * sizeof(int), stream);
    kA1<<<NCHUNK, 1024, 0, stream>>>(dstp, bcount);
    kScan98<<<1, 128, 0, stream>>>(bcount, bbase, bcursor);
    kA2<<<NCHUNK, 1024, 0, stream>>>(srcp, dstp, bcursor, ebuf);
    kB<<<NBKT, 1024, 0, stream>>>(ebuf, bbase, rowptr, esrc);

    // weight prep
    k_pack<<<256, 256, 0, stream>>>(Wl1, Wr1, Bp1);
    k_pack<<<256, 256, 0, stream>>>(Wl2, Wr2, Bp2);

    int mfma_grid = (N_NODES + 63) / 64;

    // layer 1: heads=2, C=64, concat
    k_mfma_lin<true><<<mfma_grid, 256, 0, stream>>>(x, Bp1, xl, xr, N_NODES);
    k_gat<2, true><<<(N_NODES + 3) / 4, 256, 0, stream>>>(rowptr, esrc, xl, xr, att1, b1,
                                                          nullptr, xp);
    // layer 2: heads=1, C=128, mean over 1 head = identity
    k_mfma_lin<false><<<mfma_grid, 256, 0, stream>>>(xp, Bp2, xl, xr, N_NODES);
    k_gat<1, false><<<(N_NODES + 3) / 4, 256, 0, stream>>>(rowptr, esrc, xl, xr, att2, b2,
                                                           (float*)d_out, nullptr);
}